// Round 1
// baseline (10545.601 us; speedup 1.0000x reference)
//
#include <hip/hip_runtime.h>
#include <math.h>

#define Bb 8
#define Tt 100
#define Ll 240
#define Dd 256
#define Hh 512
#define H4 2048
#define LD 61440   // Ll*Dd

// ---------------- init: zero hx/cx, q = w_b (since hx=0) ----------------
__global__ __launch_bounds__(256) void init_kernel(float* hx, float* cx, float* q_ws,
                                                   const float* __restrict__ w_b) {
  int tid = threadIdx.x;
  for (int i = tid; i < Bb * Hh; i += 256) { hx[i] = 0.f; cx[i] = 0.f; }
  for (int i = tid; i < Bb * Dd; i += 256) q_ws[i] = w_b[i & (Dd - 1)];
}

// ---------------- transpose: out[c*R + r] = in[r*C + c] ----------------
__global__ __launch_bounds__(256) void transpose_k(const float* __restrict__ in,
                                                   float* __restrict__ out, int R, int C) {
  __shared__ float tile[32][33];
  int r0 = blockIdx.x * 32, c0 = blockIdx.y * 32;
  int tx = threadIdx.x & 31, ty = threadIdx.x >> 5;
  for (int i = ty; i < 32; i += 8) {
    int r = r0 + i, c = c0 + tx;
    if (r < R && c < C) tile[i][tx] = in[(size_t)r * C + c];
  }
  __syncthreads();
  for (int i = ty; i < 32; i += 8) {
    int c = c0 + i, r = r0 + tx;
    if (r < R && c < C) out[(size_t)c * R + r] = tile[tx][i];
  }
}

// ---------------- proj GEMM: proj[r][e] = feats_row(r) . pw_w[e][:] + pw_b[e] ----------------
// r = (dt*8 + b)*240 + l for dt in [0,tc); M = tc*1920 (divisible by 64). N=K=256.
// 64x64 tile, 256 threads, 4x4 micro.
__global__ __launch_bounds__(256) void proj_gemm(const float* __restrict__ feats,
                                                 const float* __restrict__ pw_w,
                                                 const float* __restrict__ pw_b,
                                                 float* __restrict__ proj, int t0) {
  __shared__ float As[16][64];
  __shared__ float Bs[16][64];
  const int tid = threadIdx.x;
  const int m0 = blockIdx.x * 64, n0 = blockIdx.y * 64;
  const int lm = tid >> 2, lk = (tid & 3) << 2;
  const int r = m0 + lm;
  const int dtb = r / Ll, l = r % Ll;
  const int dt = dtb >> 3, b = dtb & 7;
  const float* arow = feats + ((size_t)((b * Tt) + t0 + dt) * Ll + l) * Dd;
  const float* brow = pw_w + (size_t)(n0 + lm) * Dd;
  float acc[4][4] = {};
  const int ty = tid >> 4, tx = tid & 15;
  for (int k0 = 0; k0 < Dd; k0 += 16) {
    float4 av = *(const float4*)(arow + k0 + lk);
    float4 bv = *(const float4*)(brow + k0 + lk);
    As[lk + 0][lm] = av.x; As[lk + 1][lm] = av.y; As[lk + 2][lm] = av.z; As[lk + 3][lm] = av.w;
    Bs[lk + 0][lm] = bv.x; Bs[lk + 1][lm] = bv.y; Bs[lk + 2][lm] = bv.z; Bs[lk + 3][lm] = bv.w;
    __syncthreads();
#pragma unroll
    for (int k = 0; k < 16; ++k) {
      const float4 a = *(const float4*)&As[k][ty << 2];
      const float4 bq = *(const float4*)&Bs[k][tx << 2];
      acc[0][0] += a.x * bq.x; acc[0][1] += a.x * bq.y; acc[0][2] += a.x * bq.z; acc[0][3] += a.x * bq.w;
      acc[1][0] += a.y * bq.x; acc[1][1] += a.y * bq.y; acc[1][2] += a.y * bq.z; acc[1][3] += a.y * bq.w;
      acc[2][0] += a.z * bq.x; acc[2][1] += a.z * bq.y; acc[2][2] += a.z * bq.z; acc[2][3] += a.z * bq.w;
      acc[3][0] += a.w * bq.x; acc[3][1] += a.w * bq.y; acc[3][2] += a.w * bq.z; acc[3][3] += a.w * bq.w;
    }
    __syncthreads();
  }
  const float4 bias = *(const float4*)(pw_b + n0 + (tx << 2));
#pragma unroll
  for (int i = 0; i < 4; ++i) {
    const int rr = m0 + (ty << 2) + i;
    float4 o;
    o.x = acc[i][0] + bias.x; o.y = acc[i][1] + bias.y;
    o.z = acc[i][2] + bias.z; o.w = acc[i][3] + bias.w;
    *(float4*)(proj + (size_t)rr * Dd + n0 + (tx << 2)) = o;
  }
}

// ---------------- G GEMM (per l): G[r][l][j] = feats_row(r,l) . W_ih[j][l*D:...] ----------------
// r=(dt*8+b) in [0,Mrows). 32x64 tile, 256 threads, 4x2 micro. K=256. grid=(ceilM32, 32, 240)
__global__ __launch_bounds__(256) void g_gemm(const float* __restrict__ feats,
                                              const float* __restrict__ W_ih,
                                              float* __restrict__ G, int t0, int Mrows) {
  __shared__ float As[16][32];
  __shared__ float Bs[16][64];
  const int tid = threadIdx.x;
  const int m0 = blockIdx.x * 32, n0 = blockIdx.y * 64, l = blockIdx.z;
  const int lmA = tid >> 3, lkA = (tid & 7) << 1;
  const int rA = m0 + lmA;
  const bool aval = rA < Mrows;
  const float* arow = feats;
  if (aval) arow = feats + ((size_t)((rA & 7) * Tt + t0 + (rA >> 3)) * Ll + l) * Dd;
  const int lmB = tid >> 2, lkB = (tid & 3) << 2;
  const float* brow = W_ih + (size_t)(n0 + lmB) * LD + l * Dd;
  float acc[4][2] = {};
  const int ty = tid >> 5, tx = tid & 31;
  for (int k0 = 0; k0 < Dd; k0 += 16) {
    float2 av = make_float2(0.f, 0.f);
    if (aval) av = *(const float2*)(arow + k0 + lkA);
    float4 bv = *(const float4*)(brow + k0 + lkB);
    As[lkA + 0][lmA] = av.x; As[lkA + 1][lmA] = av.y;
    Bs[lkB + 0][lmB] = bv.x; Bs[lkB + 1][lmB] = bv.y; Bs[lkB + 2][lmB] = bv.z; Bs[lkB + 3][lmB] = bv.w;
    __syncthreads();
#pragma unroll
    for (int k = 0; k < 16; ++k) {
      const float4 a = *(const float4*)&As[k][ty << 2];
      const float2 bq = *(const float2*)&Bs[k][tx << 1];
      acc[0][0] += a.x * bq.x; acc[0][1] += a.x * bq.y;
      acc[1][0] += a.y * bq.x; acc[1][1] += a.y * bq.y;
      acc[2][0] += a.z * bq.x; acc[2][1] += a.z * bq.y;
      acc[3][0] += a.w * bq.x; acc[3][1] += a.w * bq.y;
    }
    __syncthreads();
  }
#pragma unroll
  for (int i = 0; i < 4; ++i) {
    const int rr = m0 + (ty << 2) + i;
    if (rr < Mrows) {
      float2 o; o.x = acc[i][0]; o.y = acc[i][1];
      *(float2*)(G + ((size_t)rr * Ll + l) * H4 + n0 + (tx << 1)) = o;
    }
  }
}

// ---------------- per-step attention: e[b][l] = exp( sum_d tanh(proj+q)*wa + wa_b ) ----------------
// grid (8,4), 256 threads (4 waves x 15 rows each)
__global__ __launch_bounds__(256) void attn_step(const float* __restrict__ proj,
                                                 const float* __restrict__ q_ws,
                                                 const float* __restrict__ wa_w,
                                                 const float* __restrict__ wa_b,
                                                 float* __restrict__ e_buf, int dt) {
  const int b = blockIdx.x, lc = blockIdx.y;
  const int lane = threadIdx.x & 63, wv = threadIdx.x >> 6;
  __shared__ float qs[Dd];
  __shared__ float was[Dd];
  if (threadIdx.x < Dd) {
    qs[threadIdx.x] = q_ws[b * Dd + threadIdx.x];
    was[threadIdx.x] = wa_w[threadIdx.x];
  }
  __syncthreads();
  const float4 q4 = *(const float4*)&qs[lane << 2];
  const float4 w4 = *(const float4*)&was[lane << 2];
  const float wab = wa_b[0];
  for (int i = wv; i < 60; i += 4) {
    const int l = lc * 60 + i;
    const float* prow = proj + ((size_t)(dt * Bb + b) * Ll + l) * Dd;
    const float4 p4 = *(const float4*)(prow + (lane << 2));
    float s = tanhf(p4.x + q4.x) * w4.x + tanhf(p4.y + q4.y) * w4.y +
              tanhf(p4.z + q4.z) * w4.z + tanhf(p4.w + q4.w) * w4.w;
#pragma unroll
    for (int off = 32; off > 0; off >>= 1) s += __shfl_down(s, off, 64);
    if (lane == 0) e_buf[b * Ll + l] = expf(s + wab);
  }
}

// ---------------- per-step gates: gates[b][j] = (sum_l e*G)/Z + hx.W_hh^T + b_ih + b_hh ----------------
// grid (8, 32) blocks; 256 threads: p = tid>>6 (l/h partition), jl = tid&63
__global__ __launch_bounds__(256) void gates_step(const float* __restrict__ G,
                                                  const float* __restrict__ e_buf,
                                                  const float* __restrict__ hx,
                                                  const float* __restrict__ W_hhT,
                                                  const float* __restrict__ b_ih,
                                                  const float* __restrict__ b_hh,
                                                  float* __restrict__ gates,
                                                  float* __restrict__ alphas, int dt, int t) {
  const int b = blockIdx.x, jc = blockIdx.y;
  const int tid = threadIdx.x;
  const int p = tid >> 6, jl = tid & 63;
  const int j = jc * 64 + jl;
  __shared__ float es[Ll];
  __shared__ float redG[256];
  __shared__ float redH[256];
  __shared__ float zred[4];
  if (tid < Ll) es[tid] = e_buf[b * Ll + tid];
  __syncthreads();
  float gs = 0.f, zp = 0.f;
  const float* Gp = G + ((size_t)(dt * Bb + b) * Ll + p * 60) * H4 + j;
  for (int i = 0; i < 60; ++i) {
    const float e = es[p * 60 + i];
    gs += e * Gp[(size_t)i * H4];
    zp += e;
  }
  float hh = 0.f;
  const float* Wp = W_hhT + (size_t)(p * 128) * H4 + j;
  const float* hxp = hx + b * Hh + p * 128;
  for (int h = 0; h < 128; ++h) hh += hxp[h] * Wp[(size_t)h * H4];
  redG[tid] = gs;
  redH[tid] = hh;
  if (jl == 0) zred[p] = zp;
  __syncthreads();
  if (p == 0) {
    const float Z = zred[0] + zred[1] + zred[2] + zred[3];
    const float gsum = redG[jl] + redG[64 + jl] + redG[128 + jl] + redG[192 + jl];
    const float hsum = redH[jl] + redH[64 + jl] + redH[128 + jl] + redH[192 + jl];
    gates[b * H4 + j] = gsum / Z + hsum + b_ih[j] + b_hh[j];
  }
  if (jc == 0 && tid < Ll) {
    const float Z = zred[0] + zred[1] + zred[2] + zred[3];
    alphas[((size_t)t * Bb + b) * Ll + tid] = es[tid] / Z;
  }
}

// ---------------- per-step LSTM update + q for next step ----------------
// grid 8 (b); 256 threads
__global__ __launch_bounds__(256) void lstm_q_step(const float* __restrict__ gates,
                                                   float* __restrict__ cx, float* __restrict__ hx,
                                                   float* __restrict__ hx_hist,
                                                   const float* __restrict__ w_wT,
                                                   const float* __restrict__ w_b,
                                                   float* __restrict__ q_ws, int t) {
  const int b = blockIdx.x, tid = threadIdx.x;
  __shared__ float hxs[Hh];
  for (int h = tid; h < Hh; h += 256) {
    const float ig = gates[b * H4 + h];
    const float fg = gates[b * H4 + Hh + h];
    const float gg = gates[b * H4 + 2 * Hh + h];
    const float og = gates[b * H4 + 3 * Hh + h];
    const float c = cx[b * Hh + h];
    const float si = 1.f / (1.f + expf(-ig));
    const float sf = 1.f / (1.f + expf(-fg));
    const float so = 1.f / (1.f + expf(-og));
    const float cn = sf * c + si * tanhf(gg);
    const float hn = so * tanhf(cn);
    cx[b * Hh + h] = cn;
    hx[b * Hh + h] = hn;
    hxs[h] = hn;
    hx_hist[((size_t)t * Bb + b) * Hh + h] = hn;
  }
  __syncthreads();
  // q[b][d] = sum_h hx[h] * w_wT[h][d] + w_b[d]   (coalesced along d)
  const int d = tid;
  float acc = w_b[d];
  for (int h = 0; h < Hh; ++h) acc += hxs[h] * w_wT[(size_t)h * Dd + d];
  q_ws[b * Dd + d] = acc;
}

// ---------------- deferred collision MLP over all (t,b) ----------------
// grid 800 blocks, 128 threads
__global__ __launch_bounds__(128) void mlp_kernel(const float* __restrict__ hx_hist,
                                                  const float* __restrict__ m1_w, const float* __restrict__ m1_b,
                                                  const float* __restrict__ m2_w, const float* __restrict__ m2_b,
                                                  const float* __restrict__ m3_w, const float* __restrict__ m3_b,
                                                  const float* __restrict__ m4_w, const float* __restrict__ m4_b,
                                                  float* __restrict__ preds) {
  const int rb = blockIdx.x;
  const int tid = threadIdx.x;
  __shared__ float h0[Hh];
  __shared__ float x1[100];
  __shared__ float x2[50];
  __shared__ float x3[10];
  for (int i = tid; i < Hh; i += 128) h0[i] = hx_hist[(size_t)rb * Hh + i];
  __syncthreads();
  if (tid < 100) {
    float a = m1_b[tid];
    const float* w = m1_w + (size_t)tid * Hh;
    for (int h = 0; h < Hh; ++h) a += h0[h] * w[h];
    x1[tid] = fmaxf(a, 0.f);
  }
  __syncthreads();
  if (tid < 50) {
    float a = m2_b[tid];
    const float* w = m2_w + (size_t)tid * 100;
    for (int h = 0; h < 100; ++h) a += x1[h] * w[h];
    x2[tid] = fmaxf(a, 0.f);
  }
  __syncthreads();
  if (tid < 10) {
    float a = m3_b[tid];
    const float* w = m3_w + (size_t)tid * 50;
    for (int h = 0; h < 50; ++h) a += x2[h] * w[h];
    x3[tid] = fmaxf(a, 0.f);
  }
  __syncthreads();
  if (tid < 2) {
    float a = m4_b[tid];
    const float* w = m4_w + (size_t)tid * 10;
    for (int h = 0; h < 10; ++h) a += x3[h] * w[h];
    preds[(size_t)rb * 2 + tid] = a;
  }
}

extern "C" void kernel_launch(void* const* d_in, const int* in_sizes, int n_in,
                              void* d_out, int out_size, void* d_ws, size_t ws_size,
                              hipStream_t stream) {
  const float* feats = (const float*)d_in[0];   // (B,T,L,D)
  const float* pw_w  = (const float*)d_in[1];   // (D,D)
  const float* pw_b  = (const float*)d_in[2];   // (D)
  const float* w_w   = (const float*)d_in[3];   // (D,H)
  const float* w_b   = (const float*)d_in[4];   // (D)
  const float* wa_w  = (const float*)d_in[5];   // (1,D)
  const float* wa_b  = (const float*)d_in[6];   // (1)
  const float* W_ih  = (const float*)d_in[7];   // (4H, L*D)
  const float* W_hh  = (const float*)d_in[8];   // (4H, H)
  const float* b_ih  = (const float*)d_in[9];
  const float* b_hh  = (const float*)d_in[10];
  const float* m1_w  = (const float*)d_in[11];
  const float* m1_b  = (const float*)d_in[12];
  const float* m2_w  = (const float*)d_in[13];
  const float* m2_b  = (const float*)d_in[14];
  const float* m3_w  = (const float*)d_in[15];
  const float* m3_b  = (const float*)d_in[16];
  const float* m4_w  = (const float*)d_in[17];
  const float* m4_b  = (const float*)d_in[18];

  float* out = (float*)d_out;
  float* preds = out;                 // (T,B,2) = 1600
  float* alphas = out + Tt * Bb * 2;  // (T,B,L) = 192000

  float* ws = (float*)d_ws;
  size_t off = 0;
  float* hx = ws + off;       off += Bb * Hh;        // 4096
  float* cx = ws + off;       off += Bb * Hh;        // 4096
  float* q_ws = ws + off;     off += Bb * Dd;        // 2048
  float* e_buf = ws + off;    off += Bb * Ll;        // 1920
  float* gates_ws = ws + off; off += Bb * H4;        // 16384
  float* hx_hist = ws + off;  off += (size_t)Tt * Bb * Hh;     // 409600
  float* W_hhT = ws + off;    off += (size_t)H4 * Hh;          // 1048576
  float* w_wT = ws + off;     off += (size_t)Hh * Dd;          // 131072

  const size_t per_t = (size_t)Bb * Ll * Dd + (size_t)Bb * Ll * H4;  // 4,423,680 floats
  const size_t totalF = ws_size / 4;
  long availF = (long)totalF - (long)off;
  int C = (availF > 0) ? (int)(availF / (long)per_t) : 1;
  if (C < 1) C = 1;
  if (C > Tt) C = Tt;
  float* proj_ws = ws + off;
  float* G_ws = ws + off + (size_t)C * Bb * Ll * Dd;

  init_kernel<<<1, 256, 0, stream>>>(hx, cx, q_ws, w_b);
  transpose_k<<<dim3(64, 16), 256, 0, stream>>>(W_hh, W_hhT, H4, Hh);
  transpose_k<<<dim3(8, 16), 256, 0, stream>>>(w_w, w_wT, Dd, Hh);

  for (int t0 = 0; t0 < Tt; t0 += C) {
    const int tc = (C < Tt - t0) ? C : (Tt - t0);
    const int Mrows = tc * Bb;
    proj_gemm<<<dim3(tc * 30, 4), 256, 0, stream>>>(feats, pw_w, pw_b, proj_ws, t0);
    g_gemm<<<dim3((Mrows + 31) / 32, 32, 240), 256, 0, stream>>>(feats, W_ih, G_ws, t0, Mrows);
    for (int dt = 0; dt < tc; ++dt) {
      const int t = t0 + dt;
      attn_step<<<dim3(8, 4), 256, 0, stream>>>(proj_ws, q_ws, wa_w, wa_b, e_buf, dt);
      gates_step<<<dim3(8, 32), 256, 0, stream>>>(G_ws, e_buf, hx, W_hhT, b_ih, b_hh,
                                                  gates_ws, alphas, dt, t);
      lstm_q_step<<<8, 256, 0, stream>>>(gates_ws, cx, hx, hx_hist, w_wT, w_b, q_ws, t);
    }
  }
  mlp_kernel<<<800, 128, 0, stream>>>(hx_hist, m1_w, m1_b, m2_w, m2_b, m3_w, m3_b,
                                      m4_w, m4_b, preds);
}

// Round 3
// 7395.045 us; speedup vs baseline: 1.4260x; 1.4260x over previous
//
#include <hip/hip_runtime.h>
#include <math.h>

#define Bb 8
#define Tt 100
#define Ll 240
#define Dd 256
#define Hh 512
#define H4 2048
#define LD 61440   // Ll*Dd

typedef __attribute__((ext_vector_type(8))) short bf16x8;
typedef __attribute__((ext_vector_type(4))) float f32x4;

__device__ inline unsigned short f2bf_rne(float x) {
  union { float f; unsigned u; } v; v.f = x;
  unsigned r = v.u + 0x7FFFu + ((v.u >> 16) & 1u);
  return (unsigned short)(r >> 16);
}
__device__ inline float bf2f(unsigned short h) {
  union { unsigned u; float f; } v; v.u = ((unsigned)h) << 16;
  return v.f;
}

// ---------------- init: zero hx/cx, q = w_b (since hx=0) ----------------
__global__ __launch_bounds__(256) void init_kernel(float* hx, float* cx, float* q_ws,
                                                   const float* __restrict__ w_b) {
  int tid = threadIdx.x;
  for (int i = tid; i < Bb * Hh; i += 256) { hx[i] = 0.f; cx[i] = 0.f; }
  for (int i = tid; i < Bb * Dd; i += 256) q_ws[i] = w_b[i & (Dd - 1)];
}

// ---------------- transpose: out[c*R + r] = in[r*C + c] ----------------
__global__ __launch_bounds__(256) void transpose_k(const float* __restrict__ in,
                                                   float* __restrict__ out, int R, int C) {
  __shared__ float tile[32][33];
  int r0 = blockIdx.x * 32, c0 = blockIdx.y * 32;
  int tx = threadIdx.x & 31, ty = threadIdx.x >> 5;
  for (int i = ty; i < 32; i += 8) {
    int r = r0 + i, c = c0 + tx;
    if (r < R && c < C) tile[i][tx] = in[(size_t)r * C + c];
  }
  __syncthreads();
  for (int i = ty; i < 32; i += 8) {
    int c = c0 + i, r = r0 + tx;
    if (r < R && c < C) out[(size_t)c * R + r] = tile[tx][i];
  }
}

// ============ split-bf16 MFMA GEMM (3-pass fp32 emulation) ============
// MODE 0 (G):    per-l GEMM. A row rr -> feats[(b= rr&7, t0+(rr>>3), l, :)], K=256
//                B row j    -> W_ih[n0+j][l*256 + :], N=2048
//                C[rr][l][j] fp32 (G tensor)
// MODE 1 (proj): A row rr -> rr=(dtb*240+ll): feats[b=dtb&7, t0+(dtb>>3), ll, :]
//                B row e  -> pw_w[e][:], N=256; C[rr][e] = acc + pw_b[e]
// tile 64x64, BK=64, 256 threads (4 waves, 2x2), frags 2x2 of 16x16x32 bf16
template<int MODE>
__global__ __launch_bounds__(256) void mfma_gemm(const float* __restrict__ Ag,
                                                 const float* __restrict__ Bg,
                                                 const float* __restrict__ bias,
                                                 float* __restrict__ Cg,
                                                 int t0, int Mrows) {
  constexpr int LDK = 72;  // pad: 144B rows -> 16B-aligned, bank-rotate 4/row (2-way, free)
  __shared__ short Ah[64 * LDK];
  __shared__ short Al[64 * LDK];
  __shared__ short Bh[64 * LDK];
  __shared__ short Bl[64 * LDK];
  const int tid = threadIdx.x;
  const int m0 = blockIdx.x * 64;
  const int n0 = blockIdx.y * 64;
  const int l = (MODE == 0) ? blockIdx.z : 0;

  // staging: each thread owns 4 rows (s4*16 + tid>>4), 4 consecutive k at kc
  const float* aptr[4];
  const float* bptr[4];
  bool aval[4];
  const int kc = (tid & 15) << 2;
#pragma unroll
  for (int s4 = 0; s4 < 4; ++s4) {
    const int row = s4 * 16 + (tid >> 4);
    const int rr = m0 + row;
    if (MODE == 0) {
      aval[s4] = rr < Mrows;
      aptr[s4] = aval[s4]
          ? Ag + ((size_t)((rr & 7) * Tt + t0 + (rr >> 3)) * Ll + l) * Dd
          : Ag;
      bptr[s4] = Bg + (size_t)(n0 + row) * LD + (size_t)l * Dd;
    } else {
      const int dtb = rr / Ll, ll = rr - dtb * Ll;
      aval[s4] = true;
      aptr[s4] = Ag + ((size_t)((dtb & 7) * Tt + t0 + (dtb >> 3)) * Ll + ll) * Dd;
      bptr[s4] = Bg + (size_t)(n0 + row) * Dd;
    }
  }

  const int lane = tid & 63;
  const int wv = tid >> 6;
  const int wm = (wv >> 1) << 5;
  const int wn = (wv & 1) << 5;
  const int fr = lane & 15;
  const int koff = (lane >> 4) << 3;

  f32x4 acc[2][2];
#pragma unroll
  for (int i = 0; i < 2; ++i)
#pragma unroll
    for (int j = 0; j < 2; ++j)
#pragma unroll
      for (int q = 0; q < 4; ++q) acc[i][j][q] = 0.f;

  for (int k0 = 0; k0 < Dd; k0 += 64) {
#pragma unroll
    for (int s4 = 0; s4 < 4; ++s4) {
      const int row = s4 * 16 + (tid >> 4);
      float4 av = make_float4(0.f, 0.f, 0.f, 0.f);
      if (aval[s4]) av = *(const float4*)(aptr[s4] + k0 + kc);
      const float4 bv = *(const float4*)(bptr[s4] + k0 + kc);
      const int base = row * LDK + kc;
      short h0 = (short)f2bf_rne(av.x), h1 = (short)f2bf_rne(av.y),
            h2 = (short)f2bf_rne(av.z), h3 = (short)f2bf_rne(av.w);
      *(short4*)(&Ah[base]) = make_short4(h0, h1, h2, h3);
      *(short4*)(&Al[base]) = make_short4(
          (short)f2bf_rne(av.x - bf2f((unsigned short)h0)),
          (short)f2bf_rne(av.y - bf2f((unsigned short)h1)),
          (short)f2bf_rne(av.z - bf2f((unsigned short)h2)),
          (short)f2bf_rne(av.w - bf2f((unsigned short)h3)));
      short g0 = (short)f2bf_rne(bv.x), g1 = (short)f2bf_rne(bv.y),
            g2 = (short)f2bf_rne(bv.z), g3 = (short)f2bf_rne(bv.w);
      *(short4*)(&Bh[base]) = make_short4(g0, g1, g2, g3);
      *(short4*)(&Bl[base]) = make_short4(
          (short)f2bf_rne(bv.x - bf2f((unsigned short)g0)),
          (short)f2bf_rne(bv.y - bf2f((unsigned short)g1)),
          (short)f2bf_rne(bv.z - bf2f((unsigned short)g2)),
          (short)f2bf_rne(bv.w - bf2f((unsigned short)g3)));
    }
    __syncthreads();
#pragma unroll
    for (int kk = 0; kk < 64; kk += 32) {
      bf16x8 afh[2], afl[2], bfh[2], bfl[2];
#pragma unroll
      for (int i = 0; i < 2; ++i) {
        const int ba = (wm + i * 16 + fr) * LDK + kk + koff;
        afh[i] = *(const bf16x8*)&Ah[ba];
        afl[i] = *(const bf16x8*)&Al[ba];
        const int bb = (wn + i * 16 + fr) * LDK + kk + koff;
        bfh[i] = *(const bf16x8*)&Bh[bb];
        bfl[i] = *(const bf16x8*)&Bl[bb];
      }
#pragma unroll
      for (int i = 0; i < 2; ++i)
#pragma unroll
        for (int j = 0; j < 2; ++j) {
          acc[i][j] = __builtin_amdgcn_mfma_f32_16x16x32_bf16(afh[i], bfh[j], acc[i][j], 0, 0, 0);
          acc[i][j] = __builtin_amdgcn_mfma_f32_16x16x32_bf16(afh[i], bfl[j], acc[i][j], 0, 0, 0);
          acc[i][j] = __builtin_amdgcn_mfma_f32_16x16x32_bf16(afl[i], bfh[j], acc[i][j], 0, 0, 0);
        }
    }
    __syncthreads();
  }

  // epilogue: C/D layout col=lane&15, row=(lane>>4)*4+q  [m89-verified]
#pragma unroll
  for (int i = 0; i < 2; ++i) {
    const int rowf = wm + i * 16 + ((lane >> 4) << 2);
#pragma unroll
    for (int j = 0; j < 2; ++j) {
      const int colg = n0 + wn + j * 16 + fr;
#pragma unroll
      for (int q = 0; q < 4; ++q) {
        const int rr = m0 + rowf + q;
        if (MODE == 0) {
          if (rr < Mrows) Cg[((size_t)rr * Ll + l) * H4 + colg] = acc[i][j][q];
        } else {
          Cg[(size_t)rr * Dd + colg] = acc[i][j][q] + bias[colg];
        }
      }
    }
  }
}

// ---------------- per-step attention: e[b][l] = exp( sum_d tanh(proj+q)*wa + wa_b ) ----------------
__global__ __launch_bounds__(256) void attn_step(const float* __restrict__ proj,
                                                 const float* __restrict__ q_ws,
                                                 const float* __restrict__ wa_w,
                                                 const float* __restrict__ wa_b,
                                                 float* __restrict__ e_buf, int dt) {
  const int b = blockIdx.x, lc = blockIdx.y;
  const int lane = threadIdx.x & 63, wv = threadIdx.x >> 6;
  __shared__ float qs[Dd];
  __shared__ float was[Dd];
  if (threadIdx.x < Dd) {
    qs[threadIdx.x] = q_ws[b * Dd + threadIdx.x];
    was[threadIdx.x] = wa_w[threadIdx.x];
  }
  __syncthreads();
  const float4 q4 = *(const float4*)&qs[lane << 2];
  const float4 w4 = *(const float4*)&was[lane << 2];
  const float wab = wa_b[0];
  for (int i = wv; i < 60; i += 4) {
    const int l = lc * 60 + i;
    const float* prow = proj + ((size_t)(dt * Bb + b) * Ll + l) * Dd;
    const float4 p4 = *(const float4*)(prow + (lane << 2));
    float s = tanhf(p4.x + q4.x) * w4.x + tanhf(p4.y + q4.y) * w4.y +
              tanhf(p4.z + q4.z) * w4.z + tanhf(p4.w + q4.w) * w4.w;
#pragma unroll
    for (int off = 32; off > 0; off >>= 1) s += __shfl_down(s, off, 64);
    if (lane == 0) e_buf[b * Ll + l] = expf(s + wab);
  }
}

// ---------------- per-step gates ----------------
__global__ __launch_bounds__(256) void gates_step(const float* __restrict__ G,
                                                  const float* __restrict__ e_buf,
                                                  const float* __restrict__ hx,
                                                  const float* __restrict__ W_hhT,
                                                  const float* __restrict__ b_ih,
                                                  const float* __restrict__ b_hh,
                                                  float* __restrict__ gates,
                                                  float* __restrict__ alphas, int dt, int t) {
  const int b = blockIdx.x, jc = blockIdx.y;
  const int tid = threadIdx.x;
  const int p = tid >> 6, jl = tid & 63;
  const int j = jc * 64 + jl;
  __shared__ float es[Ll];
  __shared__ float redG[256];
  __shared__ float redH[256];
  __shared__ float zred[4];
  if (tid < Ll) es[tid] = e_buf[b * Ll + tid];
  __syncthreads();
  float gs = 0.f, zp = 0.f;
  const float* Gp = G + ((size_t)(dt * Bb + b) * Ll + p * 60) * H4 + j;
  for (int i = 0; i < 60; ++i) {
    const float e = es[p * 60 + i];
    gs += e * Gp[(size_t)i * H4];
    zp += e;
  }
  float hh = 0.f;
  const float* Wp = W_hhT + (size_t)(p * 128) * H4 + j;
  const float* hxp = hx + b * Hh + p * 128;
  for (int h = 0; h < 128; ++h) hh += hxp[h] * Wp[(size_t)h * H4];
  redG[tid] = gs;
  redH[tid] = hh;
  if (jl == 0) zred[p] = zp;
  __syncthreads();
  if (p == 0) {
    const float Z = zred[0] + zred[1] + zred[2] + zred[3];
    const float gsum = redG[jl] + redG[64 + jl] + redG[128 + jl] + redG[192 + jl];
    const float hsum = redH[jl] + redH[64 + jl] + redH[128 + jl] + redH[192 + jl];
    gates[b * H4 + j] = gsum / Z + hsum + b_ih[j] + b_hh[j];
  }
  if (jc == 0 && tid < Ll) {
    const float Z = zred[0] + zred[1] + zred[2] + zred[3];
    alphas[((size_t)t * Bb + b) * Ll + tid] = es[tid] / Z;
  }
}

// ---------------- per-step LSTM update + q for next step ----------------
__global__ __launch_bounds__(256) void lstm_q_step(const float* __restrict__ gates,
                                                   float* __restrict__ cx, float* __restrict__ hx,
                                                   float* __restrict__ hx_hist,
                                                   const float* __restrict__ w_wT,
                                                   const float* __restrict__ w_b,
                                                   float* __restrict__ q_ws, int t) {
  const int b = blockIdx.x, tid = threadIdx.x;
  __shared__ float hxs[Hh];
  for (int h = tid; h < Hh; h += 256) {
    const float ig = gates[b * H4 + h];
    const float fg = gates[b * H4 + Hh + h];
    const float gg = gates[b * H4 + 2 * Hh + h];
    const float og = gates[b * H4 + 3 * Hh + h];
    const float c = cx[b * Hh + h];
    const float si = 1.f / (1.f + expf(-ig));
    const float sf = 1.f / (1.f + expf(-fg));
    const float so = 1.f / (1.f + expf(-og));
    const float cn = sf * c + si * tanhf(gg);
    const float hn = so * tanhf(cn);
    cx[b * Hh + h] = cn;
    hx[b * Hh + h] = hn;
    hxs[h] = hn;
    hx_hist[((size_t)t * Bb + b) * Hh + h] = hn;
  }
  __syncthreads();
  const int d = tid;
  float acc = w_b[d];
  for (int h = 0; h < Hh; ++h) acc += hxs[h] * w_wT[(size_t)h * Dd + d];
  q_ws[b * Dd + d] = acc;
}

// ---------------- deferred collision MLP over all (t,b) ----------------
__global__ __launch_bounds__(128) void mlp_kernel(const float* __restrict__ hx_hist,
                                                  const float* __restrict__ m1_w, const float* __restrict__ m1_b,
                                                  const float* __restrict__ m2_w, const float* __restrict__ m2_b,
                                                  const float* __restrict__ m3_w, const float* __restrict__ m3_b,
                                                  const float* __restrict__ m4_w, const float* __restrict__ m4_b,
                                                  float* __restrict__ preds) {
  const int rb = blockIdx.x;
  const int tid = threadIdx.x;
  __shared__ float h0[Hh];
  __shared__ float x1[100];
  __shared__ float x2[50];
  __shared__ float x3[10];
  for (int i = tid; i < Hh; i += 128) h0[i] = hx_hist[(size_t)rb * Hh + i];
  __syncthreads();
  if (tid < 100) {
    float a = m1_b[tid];
    const float* w = m1_w + (size_t)tid * Hh;
    for (int h = 0; h < Hh; ++h) a += h0[h] * w[h];
    x1[tid] = fmaxf(a, 0.f);
  }
  __syncthreads();
  if (tid < 50) {
    float a = m2_b[tid];
    const float* w = m2_w + (size_t)tid * 100;
    for (int h = 0; h < 100; ++h) a += x1[h] * w[h];
    x2[tid] = fmaxf(a, 0.f);
  }
  __syncthreads();
  if (tid < 10) {
    float a = m3_b[tid];
    const float* w = m3_w + (size_t)tid * 50;
    for (int h = 0; h < 50; ++h) a += x2[h] * w[h];
    x3[tid] = fmaxf(a, 0.f);
  }
  __syncthreads();
  if (tid < 2) {
    float a = m4_b[tid];
    const float* w = m4_w + (size_t)tid * 10;
    for (int h = 0; h < 10; ++h) a += x3[h] * w[h];
    preds[(size_t)rb * 2 + tid] = a;
  }
}

extern "C" void kernel_launch(void* const* d_in, const int* in_sizes, int n_in,
                              void* d_out, int out_size, void* d_ws, size_t ws_size,
                              hipStream_t stream) {
  const float* feats = (const float*)d_in[0];
  const float* pw_w  = (const float*)d_in[1];
  const float* pw_b  = (const float*)d_in[2];
  const float* w_w   = (const float*)d_in[3];
  const float* w_b   = (const float*)d_in[4];
  const float* wa_w  = (const float*)d_in[5];
  const float* wa_b  = (const float*)d_in[6];
  const float* W_ih  = (const float*)d_in[7];
  const float* W_hh  = (const float*)d_in[8];
  const float* b_ih  = (const float*)d_in[9];
  const float* b_hh  = (const float*)d_in[10];
  const float* m1_w  = (const float*)d_in[11];
  const float* m1_b  = (const float*)d_in[12];
  const float* m2_w  = (const float*)d_in[13];
  const float* m2_b  = (const float*)d_in[14];
  const float* m3_w  = (const float*)d_in[15];
  const float* m3_b  = (const float*)d_in[16];
  const float* m4_w  = (const float*)d_in[17];
  const float* m4_b  = (const float*)d_in[18];

  float* out = (float*)d_out;
  float* preds = out;
  float* alphas = out + Tt * Bb * 2;

  float* ws = (float*)d_ws;
  size_t off = 0;
  float* hx = ws + off;       off += Bb * Hh;
  float* cx = ws + off;       off += Bb * Hh;
  float* q_ws = ws + off;     off += Bb * Dd;
  float* e_buf = ws + off;    off += Bb * Ll;
  float* gates_ws = ws + off; off += Bb * H4;
  float* hx_hist = ws + off;  off += (size_t)Tt * Bb * Hh;
  float* W_hhT = ws + off;    off += (size_t)H4 * Hh;
  float* w_wT = ws + off;     off += (size_t)Hh * Dd;

  const size_t per_t = (size_t)Bb * Ll * Dd + (size_t)Bb * Ll * H4;
  const size_t totalF = ws_size / 4;
  long availF = (long)totalF - (long)off;
  int C = (availF > 0) ? (int)(availF / (long)per_t) : 1;
  if (C < 1) C = 1;
  if (C > Tt) C = Tt;
  float* proj_ws = ws + off;
  float* G_ws = ws + off + (size_t)C * Bb * Ll * Dd;

  init_kernel<<<1, 256, 0, stream>>>(hx, cx, q_ws, w_b);
  transpose_k<<<dim3(64, 16), 256, 0, stream>>>(W_hh, W_hhT, H4, Hh);
  transpose_k<<<dim3(8, 16), 256, 0, stream>>>(w_w, w_wT, Dd, Hh);

  for (int t0 = 0; t0 < Tt; t0 += C) {
    const int tc = (C < Tt - t0) ? C : (Tt - t0);
    const int Mrows = tc * Bb;
    mfma_gemm<1><<<dim3(tc * 30, 4, 1), 256, 0, stream>>>(feats, pw_w, pw_b, proj_ws, t0, tc * 1920);
    mfma_gemm<0><<<dim3((Mrows + 63) / 64, 32, 240), 256, 0, stream>>>(feats, W_ih, nullptr, G_ws, t0, Mrows);
    for (int dt = 0; dt < tc; ++dt) {
      const int t = t0 + dt;
      attn_step<<<dim3(8, 4), 256, 0, stream>>>(proj_ws, q_ws, wa_w, wa_b, e_buf, dt);
      gates_step<<<dim3(8, 32), 256, 0, stream>>>(G_ws, e_buf, hx, W_hhT, b_ih, b_hh,
                                                  gates_ws, alphas, dt, t);
      lstm_q_step<<<8, 256, 0, stream>>>(gates_ws, cx, hx, hx_hist, w_wT, w_b, q_ws, t);
    }
  }
  mlp_kernel<<<800, 128, 0, stream>>>(hx_hist, m1_w, m1_b, m2_w, m2_b, m3_w, m3_b,
                                      m4_w, m4_b, preds);
}